// Round 16
// baseline (114.950 us; speedup 1.0000x reference)
//
#include <hip/hip_runtime.h>
#include <hip/hip_bf16.h>

#define DH 32
#define BSZ 128      // nodes per bucket (v_local = 7 bits)
#define NBP 1024     // padded bucket count (N <= 131072 => B <= 1024)
#define SCAT_E 3840  // edges per scatter block
#define SCAT_P (2 * SCAT_E)
#define EPT 15       // edges per thread in scatter (SCAT_E/256)
#define PRE_E 8192   // edges per precount block
#define CPG 16       // channels per sub-block in bucket_max
#define TS 4096      // pair codes per LDS tile in bucket_max
#define PAD 17       // aggL words per node (16 channels + 1 pad)

typedef short bf16x8 __attribute__((ext_vector_type(8)));
typedef float f32x4 __attribute__((ext_vector_type(4)));

__device__ __forceinline__ unsigned short f2bf(float x) {
    unsigned b = __float_as_uint(x);
    b += 0x7FFFu + ((b >> 16) & 1u);     // RNE
    return (unsigned short)(b >> 16);
}

// ---------------------------------------------------------------------------
// prep: zero gtotal AND pre-convert weights to TRANSPOSED bf16 (Wt[c][k]) so
// proj's B-fragments become single 16B vector loads. One block.
//   wbf layout: W1t [32][128] @0, W2t [32][32] @4096, Wft [32][32] @5120
// ---------------------------------------------------------------------------
__global__ __launch_bounds__(256) void prep(
    const float* __restrict__ W_in, const float* __restrict__ W_nbr,
    const float* __restrict__ W_ffnn,
    unsigned short* __restrict__ wbf, int* __restrict__ gtotal)
{
    const int t = threadIdx.x;
    for (int i = t; i < NBP; i += 256) gtotal[i] = 0;
    for (int i = t; i < 4096; i += 256) {
        int c = i >> 7, k = i & 127;
        wbf[i] = f2bf(W_in[k * 32 + c]);
    }
    for (int i = t; i < 1024; i += 256) {
        int c = i >> 5, k = i & 31;
        wbf[4096 + i] = f2bf(W_nbr[k * 32 + c]);
        wbf[5120 + i] = f2bf(W_ffnn[k * 32 + c]);
    }
}

// ---------------------------------------------------------------------------
// Exclusive scan of gtotal[0..NBP) -> gbase; gcursor = gbase. One block.
// ---------------------------------------------------------------------------
__global__ __launch_bounds__(256) void scan_buckets(
    const int* __restrict__ gtotal, int* __restrict__ gbase,
    int* __restrict__ gcursor)
{
    __shared__ int ss[256];
    const int t = threadIdx.x;
    int v0 = gtotal[4 * t], v1 = gtotal[4 * t + 1];
    int v2 = gtotal[4 * t + 2], v3 = gtotal[4 * t + 3];
    int tsum = v0 + v1 + v2 + v3;
    ss[t] = tsum;
    __syncthreads();
    for (int off = 1; off < 256; off <<= 1) {
        int y = (t >= off) ? ss[t - off] : 0;
        __syncthreads();
        ss[t] += y;
        __syncthreads();
    }
    int e = ss[t] - tsum;
    gbase[4 * t] = e;                    gcursor[4 * t] = e;
    gbase[4 * t + 1] = e + v0;           gcursor[4 * t + 1] = e + v0;
    gbase[4 * t + 2] = e + v0 + v1;      gcursor[4 * t + 2] = e + v0 + v1;
    gbase[4 * t + 3] = e + v0 + v1 + v2; gcursor[4 * t + 3] = e + v0 + v1 + v2;
}

// ---------------------------------------------------------------------------
// FUSED: blocks [0, jgrid) = MFMA node projection, ONE 16-node tile per wave
// (B-fragments = 12x 16B loads from preconverted wbf); blocks [jgrid,...) =
// precount histogram.
// Fragment layouts (m89-verified): A: row=l&15, k=(l>>4)*8+j; B: col=l&15,
// k=(l>>4)*8+j; C/D: col=l&15, row=(l>>4)*4+reg.
// ---------------------------------------------------------------------------
__global__ __launch_bounds__(256) void precount_proj(
    const int* __restrict__ src, const int* __restrict__ dst,
    int* __restrict__ gtotal, int E, int jgrid,
    const float* __restrict__ feat,
    const unsigned short* __restrict__ wbf,
    const float* __restrict__ b_in, const float* __restrict__ b_nbr,
    const float* __restrict__ b_n1, const float* __restrict__ b_ffnn,
    float* __restrict__ hpart, unsigned short* __restrict__ ub16,
    int N, int ntiles)
{
    __shared__ union {
        int hist[NBP];                       // precount path (4 KB)
        unsigned short htile[4][16 * 32];    // proj path: per-wave h bounce
    } sm;
    const int tid = threadIdx.x;

    if ((int)blockIdx.x >= jgrid) {
        // ================= precount path =================
        for (int i = tid; i < NBP; i += 256) sm.hist[i] = 0;
        __syncthreads();
        const int e0 = ((int)blockIdx.x - jgrid) * PRE_E;
        const int eend = min(e0 + PRE_E, E);
        for (int e = e0 + tid; e < eend; e += 256) {
            atomicAdd(&sm.hist[src[e] >> 7], 1);
            atomicAdd(&sm.hist[dst[e] >> 7], 1);
        }
        __syncthreads();
        for (int i = tid; i < NBP; i += 256)
            if (sm.hist[i] > 0) atomicAdd(&gtotal[i], sm.hist[i]);
        return;
    }

    // ================= proj path (MFMA, 1 tile/wave) =================
    const int wid = tid >> 6, lane = tid & 63;
    const int r16 = lane & 15, kg = lane >> 4;
    const int t = (int)blockIdx.x * 4 + wid;
    if (t >= ntiles) return;                 // wave-uniform

    const unsigned short* W1t = wbf;         // [32][128]
    const unsigned short* W2t = wbf + 4096;  // [32][32]
    const unsigned short* Wft = wbf + 5120;  // [32][32]

    // B fragments: single 16B vector loads (preconverted, transposed)
    bf16x8 B1[4][2], B2[2], Bf[2];
#pragma unroll
    for (int ks = 0; ks < 4; ++ks)
#pragma unroll
        for (int ct = 0; ct < 2; ++ct)
            B1[ks][ct] = *(const bf16x8*)&W1t[(ct * 16 + r16) * 128 + ks * 32 + kg * 8];
#pragma unroll
    for (int ct = 0; ct < 2; ++ct) {
        B2[ct] = *(const bf16x8*)&W2t[(ct * 16 + r16) * 32 + kg * 8];
        Bf[ct] = *(const bf16x8*)&Wft[(ct * 16 + r16) * 32 + kg * 8];
    }

    const float b1a = b_in[r16],            b1b = b_in[16 + r16];
    const float b2a = b_nbr[r16] + b_n1[r16];
    const float b2b = b_nbr[16 + r16] + b_n1[16 + r16];
    const float bfa = b_ffnn[r16],          bfb = b_ffnn[16 + r16];

    const int tbase = t * 16;
    const int nA = tbase + r16;
    const bool okA = (nA < N);
    const float* fr = feat + (size_t)(okA ? nA : 0) * 128;

    // A fragments: 8 consecutive k per lane (two float4 loads + cvt)
    bf16x8 A[4];
#pragma unroll
    for (int ks = 0; ks < 4; ++ks) {
        float4 p0 = make_float4(0.f, 0.f, 0.f, 0.f);
        float4 p1 = make_float4(0.f, 0.f, 0.f, 0.f);
        if (okA) {
            p0 = *(const float4*)(fr + ks * 32 + kg * 8);
            p1 = *(const float4*)(fr + ks * 32 + kg * 8 + 4);
        }
        A[ks][0] = (short)f2bf(p0.x); A[ks][1] = (short)f2bf(p0.y);
        A[ks][2] = (short)f2bf(p0.z); A[ks][3] = (short)f2bf(p0.w);
        A[ks][4] = (short)f2bf(p1.x); A[ks][5] = (short)f2bf(p1.y);
        A[ks][6] = (short)f2bf(p1.z); A[ks][7] = (short)f2bf(p1.w);
    }

    // GEMM1: h-tile = feat-tile @ W_in + b_in
    f32x4 acc0 = {b1a, b1a, b1a, b1a};
    f32x4 acc1 = {b1b, b1b, b1b, b1b};
#pragma unroll
    for (int ks = 0; ks < 4; ++ks) {
        acc0 = __builtin_amdgcn_mfma_f32_16x16x32_bf16(A[ks], B1[ks][0], acc0, 0, 0, 0);
        acc1 = __builtin_amdgcn_mfma_f32_16x16x32_bf16(A[ks], B1[ks][1], acc1, 0, 0, 0);
    }

    // bounce h (bf16) through wave-private LDS: C-layout -> A-layout
    unsigned short* hl = &sm.htile[wid][0];
#pragma unroll
    for (int r = 0; r < 4; ++r) {
        hl[(kg * 4 + r) * 32 + r16]      = f2bf(acc0[r]);
        hl[(kg * 4 + r) * 32 + 16 + r16] = f2bf(acc1[r]);
    }
    asm volatile("s_waitcnt lgkmcnt(0)" ::: "memory");
    bf16x8 A2 = *reinterpret_cast<const bf16x8*>(&hl[r16 * 32 + kg * 8]);

    // GEMM2 (u) and hpart, K=32 single step each
    f32x4 u0 = {b2a, b2a, b2a, b2a};
    f32x4 u1 = {b2b, b2b, b2b, b2b};
    u0 = __builtin_amdgcn_mfma_f32_16x16x32_bf16(A2, B2[0], u0, 0, 0, 0);
    u1 = __builtin_amdgcn_mfma_f32_16x16x32_bf16(A2, B2[1], u1, 0, 0, 0);
    f32x4 g0 = {bfa, bfa, bfa, bfa};
    f32x4 g1 = {bfb, bfb, bfb, bfb};
    g0 = __builtin_amdgcn_mfma_f32_16x16x32_bf16(A2, Bf[0], g0, 0, 0, 0);
    g1 = __builtin_amdgcn_mfma_f32_16x16x32_bf16(A2, Bf[1], g1, 0, 0, 0);

    // stores: lane covers nodes tbase + kg*4 + r, channel r16 (+16)
#pragma unroll
    for (int r = 0; r < 4; ++r) {
        const int n2 = tbase + kg * 4 + r;
        if (n2 < N) {
            float s0 = 1.0f / (1.0f + __expf(-u0[r]));
            float s1 = 1.0f / (1.0f + __expf(-u1[r]));
            ub16[(size_t)n2 * 16 + r16]       = f2bf(s0);  // half 0
            ub16[((size_t)N + n2) * 16 + r16] = f2bf(s1);  // half 1
            hpart[(size_t)n2 * 32 + r16]      = g0[r];
            hpart[(size_t)n2 * 32 + 16 + r16] = g1[r];
        }
    }
}

// ---------------------------------------------------------------------------
// Bucket-granular scatter (standalone; 38.9 KB LDS, 4 blocks/CU).
// Bucket low byte rides in code bits 24..31; recovered via cur containment.
// ---------------------------------------------------------------------------
__global__ __launch_bounds__(256) void bucket_scatter(
    const int* __restrict__ src, const int* __restrict__ dst,
    int* __restrict__ gcursor, unsigned* __restrict__ pairs_g,
    int E, int B)
{
    __shared__ unsigned s_code[SCAT_P];     // 30 KB
    __shared__ int s_cur[NBP];              // 4 KB (counts -> starts -> ends)
    __shared__ int s_gbL[NBP];              // 4 KB (also scan temp [0..3])

    const int tid = threadIdx.x;
    const int e0 = blockIdx.x * SCAT_E;
    const int eend = min(e0 + SCAT_E, E);
    const int np = 2 * (eend - e0);

    for (int i = tid; i < NBP; i += 256) s_cur[i] = 0;
    __syncthreads();

    int es[EPT], dr[EPT];
#pragma unroll
    for (int j = 0; j < EPT; ++j) {
        int e = e0 + tid + j * 256;
        bool ok = (e < eend);
        es[j] = ok ? src[e] : -1;
        dr[j] = ok ? dst[e] : -1;
    }
#pragma unroll
    for (int j = 0; j < EPT; ++j) {
        if (es[j] >= 0) {
            atomicAdd(&s_cur[es[j] >> 7], 1);
            atomicAdd(&s_cur[dr[j] >> 7], 1);
        }
    }
    __syncthreads();

    // in-place exclusive scan of cur (counts -> starts); shfl-based
    {
        const int lane = tid & 63;
        const int w = tid >> 6;
        int v0 = s_cur[4 * tid], v1 = s_cur[4 * tid + 1];
        int v2 = s_cur[4 * tid + 2], v3 = s_cur[4 * tid + 3];
        int tsum = v0 + v1 + v2 + v3;
        int x = tsum;
#pragma unroll
        for (int off = 1; off < 64; off <<= 1) {
            int y = __shfl_up(x, off, 64);
            x += (lane >= off) ? y : 0;
        }
        if (lane == 63) s_gbL[w] = x;       // wave totals (temp use)
        __syncthreads();
        int woff = 0;
#pragma unroll
        for (int k = 0; k < 4; ++k) woff += (k < w) ? s_gbL[k] : 0;
        int ebase = woff + x - tsum;
        __syncthreads();                    // all reads of cur done
        s_cur[4 * tid] = ebase;
        s_cur[4 * tid + 1] = ebase + v0;
        s_cur[4 * tid + 2] = ebase + v0 + v1;
        s_cur[4 * tid + 3] = ebase + v0 + v1 + v2;
    }
    __syncthreads();

    // rank + reorder into LDS; bucket low byte in code[31:24]
#pragma unroll
    for (int j = 0; j < EPT; ++j) {
        if (es[j] >= 0) {
            int s = es[j], d = dr[j];
            int bs = s >> 7, bd = d >> 7;
            unsigned cs = ((unsigned)(bs & 255) << 24) |
                          ((unsigned)(s & 127) << 17) | (unsigned)d;
            unsigned cd = ((unsigned)(bd & 255) << 24) |
                          ((unsigned)(d & 127) << 17) | (unsigned)s;
            int p1 = atomicAdd(&s_cur[bs], 1);
            s_code[p1] = cs;
            int p2 = atomicAdd(&s_cur[bd], 1);
            s_code[p2] = cd;
        }
    }
    __syncthreads();
    // cur[b] = segment END; start(b) = cur[b-1] (segments packed)

    for (int b = tid; b < B; b += 256) {
        int end = s_cur[b];
        int start = b ? s_cur[b - 1] : 0;
        int c = end - start;
        if (c > 0) {
            int gw = atomicAdd(&gcursor[b], c);
            s_gbL[b] = gw - start;
        }
    }
    __syncthreads();

    // coalesced run writes; recover bucket via low byte + containment
    for (int i = tid; i < np; i += 256) {
        unsigned code = s_code[i];
        int cc = (int)(code >> 24);
#pragma unroll
        for (int k = 0; k < 3; ++k) {
            int hi2 = s_cur[cc];
            int lo2 = cc ? s_cur[cc - 1] : 0;
            bool in = (i < hi2) && (i >= lo2);
            cc = in ? cc : cc + 256;
        }
        pairs_g[s_gbL[cc] + i] = code & 0x00FFFFFFu;
    }
}

// ---------------------------------------------------------------------------
// Per-bucket segment max in LDS. XCD-aware decode: q = xcd>=4 so each XCD's
// L2 caches only ITS 3.2MB u-table. 16-deep unrolled gathers per lane.
// ---------------------------------------------------------------------------
__global__ __launch_bounds__(256) void bucket_max(
    const unsigned* __restrict__ pairs_g, const int* __restrict__ gbase,
    const int* __restrict__ gtotal, const unsigned* __restrict__ ub32,
    float* __restrict__ agg, int N, int B)
{
    __shared__ unsigned aggL[BSZ * PAD];   // 8.7 KB
    __shared__ int degL[BSZ];              // 0.5 KB
    __shared__ unsigned tile[TS];          // 16 KB

    const int tid = threadIdx.x;
    const int bid = blockIdx.x;
    const int xcd = bid & 7;
    const int q = xcd >> 2;                          // channel half by XCD group
    const int b = (bid >> 3) * 4 + (xcd & 3);
    if (b >= B) return;
    const int v0 = b * BSZ;
    const unsigned* ut = ub32 + (size_t)q * N * 8;   // 8 u32 per node

    for (int i = tid; i < BSZ * PAD; i += 256) aggL[i] = 0u;
    for (int i = tid; i < BSZ; i += 256) degL[i] = 0;
    __syncthreads();

    const int start = gbase[b];
    const int cnt = gtotal[b];
    const int gg = tid >> 3;       // 32 groups of 8 lanes
    const int cl = tid & 7;

    for (int t0 = 0; t0 < cnt; t0 += TS) {
        const int tn = min(TS, cnt - t0);
        for (int i = tid; i < tn; i += 256) tile[i] = pairs_g[start + t0 + i];
        __syncthreads();

        const int kmax = (tn - gg + 31) >> 5;   // <=0 if gg >= tn
        const int pm = tn - 1;
        for (int kk = 0; kk < kmax; kk += 16) {
            unsigned cc[16], xx[16];
#pragma unroll
            for (int u = 0; u < 16; ++u)
                cc[u] = tile[min(gg + (kk + u) * 32, pm)];
#pragma unroll
            for (int u = 0; u < 16; ++u)
                xx[u] = ut[(size_t)(cc[u] & 0x1FFFF) * 8 + cl];
#pragma unroll
            for (int u = 0; u < 16; ++u) {
                atomicMax(&aggL[(cc[u] >> 17) * PAD + 2 * cl], (xx[u] & 0xFFFFu) << 16);
                atomicMax(&aggL[(cc[u] >> 17) * PAD + 2 * cl + 1], xx[u] & 0xFFFF0000u);
            }
            if (cl == 0) {
#pragma unroll
                for (int u = 0; u < 16; ++u)
                    if (gg + (kk + u) * 32 < tn) atomicAdd(&degL[cc[u] >> 17], 1);
            }
        }
        __syncthreads();
    }

    for (int i = tid; i < BSZ * CPG; i += 256) {
        int vl = i >> 4;
        int v = v0 + vl;
        if (v < N) {
            float val = (degL[vl] > 1) ? __uint_as_float(aggL[vl * PAD + (i & 15)]) : 0.f;
            agg[(size_t)v * DH + q * CPG + (i & 15)] = val;
        }
    }
}

// ---------------------------------------------------------------------------
// out = hpart + agg @ W_ffnn[32:64]; wave-uniform weight loads, no LDS.
// ---------------------------------------------------------------------------
__global__ __launch_bounds__(256) void fin(
    const float* __restrict__ hpart, const float* __restrict__ agg,
    const float* __restrict__ W_ffnn, float* __restrict__ out, int N)
{
    const int node = blockIdx.x * 256 + threadIdx.x;
    if (node >= N) return;

    const float4* hr = (const float4*)(hpart + (size_t)node * 32);
    const float4* ar = (const float4*)(agg + (size_t)node * 32);

    float acc[32], a[32];
#pragma unroll
    for (int c4 = 0; c4 < 8; ++c4) {
        float4 v = hr[c4];
        acc[c4 * 4 + 0] = v.x; acc[c4 * 4 + 1] = v.y;
        acc[c4 * 4 + 2] = v.z; acc[c4 * 4 + 3] = v.w;
        float4 w = ar[c4];
        a[c4 * 4 + 0] = w.x; a[c4 * 4 + 1] = w.y;
        a[c4 * 4 + 2] = w.z; a[c4 * 4 + 3] = w.w;
    }

    const float* W2h = W_ffnn + 1024;   // rows 32..63
#pragma unroll
    for (int k = 0; k < 32; ++k) {
        const float hv = a[k];
        const float* wr = W2h + k * 32;
#pragma unroll
        for (int c = 0; c < 32; ++c)
            acc[c] = fmaf(hv, wr[c], acc[c]);
    }

    float4* orow = (float4*)(out + (size_t)node * 32);
#pragma unroll
    for (int c4 = 0; c4 < 8; ++c4)
        orow[c4] = make_float4(acc[c4 * 4 + 0], acc[c4 * 4 + 1],
                               acc[c4 * 4 + 2], acc[c4 * 4 + 3]);
}

// ---------------------------------------------------------------------------
extern "C" void kernel_launch(void* const* d_in, const int* in_sizes, int n_in,
                              void* d_out, int out_size, void* d_ws, size_t ws_size,
                              hipStream_t stream)
{
    const float* feat   = (const float*)d_in[0];
    const int*   src    = (const int*)d_in[1];
    const int*   dst    = (const int*)d_in[2];
    const float* W_in   = (const float*)d_in[3];
    const float* b_in   = (const float*)d_in[4];
    const float* W_nbr  = (const float*)d_in[5];
    const float* b_nbr  = (const float*)d_in[6];
    const float* b_n1   = (const float*)d_in[7];
    const float* W_ffnn = (const float*)d_in[8];
    const float* b_ffnn = (const float*)d_in[9];
    float* out = (float*)d_out;

    const int N = in_sizes[0] / 128;   // 100000 (N <= 131072 required by packing)
    const int E = in_sizes[1];
    const int B = (N + BSZ - 1) / BSZ; // 782 buckets (<= NBP)
    const int ntiles = (N + 15) / 16;  // 6250 16-node tiles

    // u (bf16, channel-split, 6.4MB) aliases d_out (12.8MB): written by the
    // proj path, consumed by bucket_max, then fin overwrites out.
    unsigned short* ub16 = (unsigned short*)out;
    float* hpart   = (float*)d_ws;                    // N*32 f32
    float* agg     = hpart + (size_t)N * DH;          // N*32 f32
    int*   gtotal  = (int*)(agg + (size_t)N * DH);    // NBP
    int*   gbase   = gtotal + NBP;                    // NBP
    int*   gcursor = gbase + NBP;                     // NBP
    unsigned* pairs_g = (unsigned*)(gcursor + NBP);   // 2E u32
    unsigned short* wbf = (unsigned short*)(pairs_g + 2 * (size_t)E);  // 6144 u16

    const int egrid = (E + SCAT_E - 1) / SCAT_E;      // 261
    const int pgrid = (E + PRE_E - 1) / PRE_E;        // 123
    const int jgrid = (ntiles + 3) / 4;               // 1563 proj blocks (1 tile/wave)
    const int npb = (N + 255) / 256;                  // 391

    prep<<<1, 256, 0, stream>>>(W_in, W_nbr, W_ffnn, wbf, gtotal);
    precount_proj<<<jgrid + pgrid, 256, 0, stream>>>(
        src, dst, gtotal, E, jgrid,
        feat, wbf, b_in, b_nbr, b_n1, b_ffnn,
        hpart, ub16, N, ntiles);
    scan_buckets<<<1, 256, 0, stream>>>(gtotal, gbase, gcursor);
    bucket_scatter<<<egrid, 256, 0, stream>>>(src, dst, gcursor, pairs_g, E, B);
    bucket_max<<<((B + 3) / 4) * 8, 256, 0, stream>>>(
        pairs_g, gbase, gtotal, (const unsigned*)ub16, agg, N, B);
    fin<<<npb, 256, 0, stream>>>(hpart, agg, W_ffnn, out, N);
}

// Round 17
// 105.748 us; speedup vs baseline: 1.0870x; 1.0870x over previous
//
#include <hip/hip_runtime.h>
#include <hip/hip_bf16.h>

#define DH 32
#define BSZ 128      // nodes per bucket (v_local = 7 bits)
#define NBP 1024     // padded bucket count (N <= 131072 => B <= 1024)
#define SCAT_E 3840  // edges per scatter block
#define SCAT_P (2 * SCAT_E)
#define EPT 15       // edges per thread in scatter (SCAT_E/256)
#define PRE_E 8192   // edges per precount block
#define CPG 16       // channels per sub-block in bucket_max
#define TS 4096      // pair codes per LDS tile in bucket_max
#define PAD 17       // aggL words per node (16 channels + 1 pad)
#define TPW 2        // 16-node tiles per wave in proj

typedef short bf16x8 __attribute__((ext_vector_type(8)));
typedef float f32x4 __attribute__((ext_vector_type(4)));

__device__ __forceinline__ unsigned short f2bf(float x) {
    unsigned b = __float_as_uint(x);
    b += 0x7FFFu + ((b >> 16) & 1u);     // RNE
    return (unsigned short)(b >> 16);
}

// ---------------------------------------------------------------------------
// pre2: blocks [0, pgrid) = per-bucket endpoint histogram; block pgrid =
// weight preconversion to TRANSPOSED bf16 (Wt[c][k]) into wbf.
//   wbf layout: W1t [32][128] @0, W2t [32][32] @4096, Wft [32][32] @5120
// ---------------------------------------------------------------------------
__global__ __launch_bounds__(256) void pre2(
    const int* __restrict__ src, const int* __restrict__ dst,
    int* __restrict__ gtotal, int E, int pgrid,
    const float* __restrict__ W_in, const float* __restrict__ W_nbr,
    const float* __restrict__ W_ffnn, unsigned short* __restrict__ wbf)
{
    __shared__ int hist[NBP];
    const int tid = threadIdx.x;

    if ((int)blockIdx.x == pgrid) {
        for (int i = tid; i < 4096; i += 256) {
            int c = i >> 7, k = i & 127;
            wbf[i] = f2bf(W_in[k * 32 + c]);
        }
        for (int i = tid; i < 1024; i += 256) {
            int c = i >> 5, k = i & 31;
            wbf[4096 + i] = f2bf(W_nbr[k * 32 + c]);
            wbf[5120 + i] = f2bf(W_ffnn[k * 32 + c]);
        }
        return;
    }

    for (int i = tid; i < NBP; i += 256) hist[i] = 0;
    __syncthreads();
    const int e0 = blockIdx.x * PRE_E;
    const int eend = min(e0 + PRE_E, E);
    for (int e = e0 + tid; e < eend; e += 256) {
        atomicAdd(&hist[src[e] >> 7], 1);
        atomicAdd(&hist[dst[e] >> 7], 1);
    }
    __syncthreads();
    for (int i = tid; i < NBP; i += 256)
        if (hist[i] > 0) atomicAdd(&gtotal[i], hist[i]);
}

// ---------------------------------------------------------------------------
// Exclusive scan of gtotal[0..NBP) -> gbase; gcursor = gbase. One block.
// ---------------------------------------------------------------------------
__global__ __launch_bounds__(256) void scan_buckets(
    const int* __restrict__ gtotal, int* __restrict__ gbase,
    int* __restrict__ gcursor)
{
    __shared__ int ss[256];
    const int t = threadIdx.x;
    int v0 = gtotal[4 * t], v1 = gtotal[4 * t + 1];
    int v2 = gtotal[4 * t + 2], v3 = gtotal[4 * t + 3];
    int tsum = v0 + v1 + v2 + v3;
    ss[t] = tsum;
    __syncthreads();
    for (int off = 1; off < 256; off <<= 1) {
        int y = (t >= off) ? ss[t - off] : 0;
        __syncthreads();
        ss[t] += y;
        __syncthreads();
    }
    int e = ss[t] - tsum;
    gbase[4 * t] = e;                    gcursor[4 * t] = e;
    gbase[4 * t + 1] = e + v0;           gcursor[4 * t + 1] = e + v0;
    gbase[4 * t + 2] = e + v0 + v1;      gcursor[4 * t + 2] = e + v0 + v1;
    gbase[4 * t + 3] = e + v0 + v1 + v2; gcursor[4 * t + 3] = e + v0 + v1 + v2;
}

// ---------------------------------------------------------------------------
// FUSED scatproj: blocks [0, egrid) = bucket-granular scatter (38.9 KB LDS);
// blocks [egrid, egrid+jgrid) = MFMA node projection (TPW tiles/wave, wbf
// preconverted weights, 4 KB LDS). The two are independent and latency-bound
// on different resources; co-residency overlaps them.
// MFMA fragment layouts (m89-verified): A: row=l&15, k=(l>>4)*8+j;
// B: col=l&15, k=(l>>4)*8+j; C/D: col=l&15, row=(l>>4)*4+reg.
// ---------------------------------------------------------------------------
union SPSmem {
    struct {                                // 38.9 KB (scatter)
        unsigned code[SCAT_P];              // 30 KB
        int cur[NBP];                       // 4 KB (counts -> starts -> ends)
        int gbL[NBP];                       // 4 KB (also scan temp [0..3])
    } sc;
    struct {                                // 4 KB (proj)
        unsigned short htile[4][16 * 32];   // per-wave h bounce
    } pj;
};

__global__ __launch_bounds__(256) void scatproj(
    const int* __restrict__ src, const int* __restrict__ dst,
    int* __restrict__ gcursor, unsigned* __restrict__ pairs_g,
    int E, int B, int egrid,
    const float* __restrict__ feat,
    const unsigned short* __restrict__ wbf,
    const float* __restrict__ b_in, const float* __restrict__ b_nbr,
    const float* __restrict__ b_n1, const float* __restrict__ b_ffnn,
    float* __restrict__ hpart, unsigned short* __restrict__ ub16,
    int N, int ntiles)
{
    __shared__ SPSmem sm;
    const int tid = threadIdx.x;

    if ((int)blockIdx.x < egrid) {
        // ================= scatter path =================
        const int e0 = blockIdx.x * SCAT_E;
        const int eend = min(e0 + SCAT_E, E);
        const int np = 2 * (eend - e0);

        for (int i = tid; i < NBP; i += 256) sm.sc.cur[i] = 0;
        __syncthreads();

        int es[EPT], dr[EPT];
#pragma unroll
        for (int j = 0; j < EPT; ++j) {
            int e = e0 + tid + j * 256;
            bool ok = (e < eend);
            es[j] = ok ? src[e] : -1;
            dr[j] = ok ? dst[e] : -1;
        }
#pragma unroll
        for (int j = 0; j < EPT; ++j) {
            if (es[j] >= 0) {
                atomicAdd(&sm.sc.cur[es[j] >> 7], 1);
                atomicAdd(&sm.sc.cur[dr[j] >> 7], 1);
            }
        }
        __syncthreads();

        // in-place exclusive scan of cur (counts -> starts); shfl-based
        {
            const int lane = tid & 63;
            const int w = tid >> 6;
            int v0 = sm.sc.cur[4 * tid], v1 = sm.sc.cur[4 * tid + 1];
            int v2 = sm.sc.cur[4 * tid + 2], v3 = sm.sc.cur[4 * tid + 3];
            int tsum = v0 + v1 + v2 + v3;
            int x = tsum;
#pragma unroll
            for (int off = 1; off < 64; off <<= 1) {
                int y = __shfl_up(x, off, 64);
                x += (lane >= off) ? y : 0;
            }
            if (lane == 63) sm.sc.gbL[w] = x;   // wave totals (temp use)
            __syncthreads();
            int woff = 0;
#pragma unroll
            for (int k = 0; k < 4; ++k) woff += (k < w) ? sm.sc.gbL[k] : 0;
            int ebase = woff + x - tsum;
            __syncthreads();                    // all reads of cur done
            sm.sc.cur[4 * tid] = ebase;
            sm.sc.cur[4 * tid + 1] = ebase + v0;
            sm.sc.cur[4 * tid + 2] = ebase + v0 + v1;
            sm.sc.cur[4 * tid + 3] = ebase + v0 + v1 + v2;
        }
        __syncthreads();

        // rank + reorder into LDS; bucket low byte in code[31:24]
#pragma unroll
        for (int j = 0; j < EPT; ++j) {
            if (es[j] >= 0) {
                int s = es[j], d = dr[j];
                int bs = s >> 7, bd = d >> 7;
                unsigned cs = ((unsigned)(bs & 255) << 24) |
                              ((unsigned)(s & 127) << 17) | (unsigned)d;
                unsigned cd = ((unsigned)(bd & 255) << 24) |
                              ((unsigned)(d & 127) << 17) | (unsigned)s;
                int p1 = atomicAdd(&sm.sc.cur[bs], 1);
                sm.sc.code[p1] = cs;
                int p2 = atomicAdd(&sm.sc.cur[bd], 1);
                sm.sc.code[p2] = cd;
            }
        }
        __syncthreads();
        // cur[b] = segment END; start(b) = cur[b-1] (segments packed)

        for (int b = tid; b < B; b += 256) {
            int end = sm.sc.cur[b];
            int start = b ? sm.sc.cur[b - 1] : 0;
            int c = end - start;
            if (c > 0) {
                int gw = atomicAdd(&gcursor[b], c);
                sm.sc.gbL[b] = gw - start;
            }
        }
        __syncthreads();

        // coalesced run writes; recover bucket via low byte + containment
        for (int i = tid; i < np; i += 256) {
            unsigned code = sm.sc.code[i];
            int cc = (int)(code >> 24);
#pragma unroll
            for (int k = 0; k < 3; ++k) {
                int hi2 = sm.sc.cur[cc];
                int lo2 = cc ? sm.sc.cur[cc - 1] : 0;
                bool in = (i < hi2) && (i >= lo2);
                cc = in ? cc : cc + 256;
            }
            pairs_g[sm.sc.gbL[cc] + i] = code & 0x00FFFFFFu;
        }
        return;
    }

    // ================= proj path (MFMA, TPW tiles/wave) =================
    const int wid = tid >> 6, lane = tid & 63;
    const int r16 = lane & 15, kg = lane >> 4;
    const int w = ((int)blockIdx.x - egrid) * 4 + wid;
    const int t0 = w * TPW;
    if (t0 >= ntiles) return;                // wave-uniform

    const unsigned short* W1t = wbf;         // [32][128]
    const unsigned short* W2t = wbf + 4096;  // [32][32]
    const unsigned short* Wft = wbf + 5120;  // [32][32]

    // B fragments: single 16B vector loads (preconverted, transposed)
    bf16x8 B1[4][2], B2[2], Bf[2];
#pragma unroll
    for (int ks = 0; ks < 4; ++ks)
#pragma unroll
        for (int ct = 0; ct < 2; ++ct)
            B1[ks][ct] = *(const bf16x8*)&W1t[(ct * 16 + r16) * 128 + ks * 32 + kg * 8];
#pragma unroll
    for (int ct = 0; ct < 2; ++ct) {
        B2[ct] = *(const bf16x8*)&W2t[(ct * 16 + r16) * 32 + kg * 8];
        Bf[ct] = *(const bf16x8*)&Wft[(ct * 16 + r16) * 32 + kg * 8];
    }

    const float b1a = b_in[r16],            b1b = b_in[16 + r16];
    const float b2a = b_nbr[r16] + b_n1[r16];
    const float b2b = b_nbr[16 + r16] + b_n1[16 + r16];
    const float bfa = b_ffnn[r16],          bfb = b_ffnn[16 + r16];

    unsigned short* hl = &sm.pj.htile[wid][0];

#pragma unroll
    for (int i = 0; i < TPW; ++i) {
        const int ti = t0 + i;
        const bool tv = (ti < ntiles);
        const int t = tv ? ti : ntiles - 1;
        const int tbase = t * 16;
        const int nA = tbase + r16;
        const bool okA = tv && (nA < N);
        const float* fr = feat + (size_t)(okA ? nA : 0) * 128;

        // A fragments: 8 consecutive k per lane (two float4 loads + cvt)
        bf16x8 A[4];
#pragma unroll
        for (int ks = 0; ks < 4; ++ks) {
            float4 p0 = make_float4(0.f, 0.f, 0.f, 0.f);
            float4 p1 = make_float4(0.f, 0.f, 0.f, 0.f);
            if (okA) {
                p0 = *(const float4*)(fr + ks * 32 + kg * 8);
                p1 = *(const float4*)(fr + ks * 32 + kg * 8 + 4);
            }
            A[ks][0] = (short)f2bf(p0.x); A[ks][1] = (short)f2bf(p0.y);
            A[ks][2] = (short)f2bf(p0.z); A[ks][3] = (short)f2bf(p0.w);
            A[ks][4] = (short)f2bf(p1.x); A[ks][5] = (short)f2bf(p1.y);
            A[ks][6] = (short)f2bf(p1.z); A[ks][7] = (short)f2bf(p1.w);
        }

        // GEMM1: h-tile = feat-tile @ W_in + b_in
        f32x4 acc0 = {b1a, b1a, b1a, b1a};
        f32x4 acc1 = {b1b, b1b, b1b, b1b};
#pragma unroll
        for (int ks = 0; ks < 4; ++ks) {
            acc0 = __builtin_amdgcn_mfma_f32_16x16x32_bf16(A[ks], B1[ks][0], acc0, 0, 0, 0);
            acc1 = __builtin_amdgcn_mfma_f32_16x16x32_bf16(A[ks], B1[ks][1], acc1, 0, 0, 0);
        }

        // bounce h (bf16) through wave-private LDS: C-layout -> A-layout
#pragma unroll
        for (int r = 0; r < 4; ++r) {
            hl[(kg * 4 + r) * 32 + r16]      = f2bf(acc0[r]);
            hl[(kg * 4 + r) * 32 + 16 + r16] = f2bf(acc1[r]);
        }
        asm volatile("s_waitcnt lgkmcnt(0)" ::: "memory");
        bf16x8 A2 = *reinterpret_cast<const bf16x8*>(&hl[r16 * 32 + kg * 8]);

        // GEMM2 (u) and hpart, K=32 single step each
        f32x4 u0 = {b2a, b2a, b2a, b2a};
        f32x4 u1 = {b2b, b2b, b2b, b2b};
        u0 = __builtin_amdgcn_mfma_f32_16x16x32_bf16(A2, B2[0], u0, 0, 0, 0);
        u1 = __builtin_amdgcn_mfma_f32_16x16x32_bf16(A2, B2[1], u1, 0, 0, 0);
        f32x4 g0 = {bfa, bfa, bfa, bfa};
        f32x4 g1 = {bfb, bfb, bfb, bfb};
        g0 = __builtin_amdgcn_mfma_f32_16x16x32_bf16(A2, Bf[0], g0, 0, 0, 0);
        g1 = __builtin_amdgcn_mfma_f32_16x16x32_bf16(A2, Bf[1], g1, 0, 0, 0);

        // stores: lane covers nodes tbase + kg*4 + r, channel r16 (+16)
#pragma unroll
        for (int r = 0; r < 4; ++r) {
            const int n2 = tbase + kg * 4 + r;
            if (tv && n2 < N) {
                float s0 = 1.0f / (1.0f + __expf(-u0[r]));
                float s1 = 1.0f / (1.0f + __expf(-u1[r]));
                ub16[(size_t)n2 * 16 + r16]       = f2bf(s0);  // half 0
                ub16[((size_t)N + n2) * 16 + r16] = f2bf(s1);  // half 1
                hpart[(size_t)n2 * 32 + r16]      = g0[r];
                hpart[(size_t)n2 * 32 + 16 + r16] = g1[r];
            }
        }
    }
}

// ---------------------------------------------------------------------------
// Per-bucket segment max in LDS. XCD-aware decode: q = xcd>=4 so each XCD's
// L2 caches only ITS 3.2MB u-table. 16-deep unrolled gathers per lane.
// ---------------------------------------------------------------------------
__global__ __launch_bounds__(256) void bucket_max(
    const unsigned* __restrict__ pairs_g, const int* __restrict__ gbase,
    const int* __restrict__ gtotal, const unsigned* __restrict__ ub32,
    float* __restrict__ agg, int N, int B)
{
    __shared__ unsigned aggL[BSZ * PAD];   // 8.7 KB
    __shared__ int degL[BSZ];              // 0.5 KB
    __shared__ unsigned tile[TS];          // 16 KB

    const int tid = threadIdx.x;
    const int bid = blockIdx.x;
    const int xcd = bid & 7;
    const int q = xcd >> 2;                          // channel half by XCD group
    const int b = (bid >> 3) * 4 + (xcd & 3);
    if (b >= B) return;
    const int v0 = b * BSZ;
    const unsigned* ut = ub32 + (size_t)q * N * 8;   // 8 u32 per node

    for (int i = tid; i < BSZ * PAD; i += 256) aggL[i] = 0u;
    for (int i = tid; i < BSZ; i += 256) degL[i] = 0;
    __syncthreads();

    const int start = gbase[b];
    const int cnt = gtotal[b];
    const int gg = tid >> 3;       // 32 groups of 8 lanes
    const int cl = tid & 7;

    for (int t0 = 0; t0 < cnt; t0 += TS) {
        const int tn = min(TS, cnt - t0);
        for (int i = tid; i < tn; i += 256) tile[i] = pairs_g[start + t0 + i];
        __syncthreads();

        const int kmax = (tn - gg + 31) >> 5;   // <=0 if gg >= tn
        const int pm = tn - 1;
        for (int kk = 0; kk < kmax; kk += 16) {
            unsigned cc[16], xx[16];
#pragma unroll
            for (int u = 0; u < 16; ++u)
                cc[u] = tile[min(gg + (kk + u) * 32, pm)];
#pragma unroll
            for (int u = 0; u < 16; ++u)
                xx[u] = ut[(size_t)(cc[u] & 0x1FFFF) * 8 + cl];
#pragma unroll
            for (int u = 0; u < 16; ++u) {
                atomicMax(&aggL[(cc[u] >> 17) * PAD + 2 * cl], (xx[u] & 0xFFFFu) << 16);
                atomicMax(&aggL[(cc[u] >> 17) * PAD + 2 * cl + 1], xx[u] & 0xFFFF0000u);
            }
            if (cl == 0) {
#pragma unroll
                for (int u = 0; u < 16; ++u)
                    if (gg + (kk + u) * 32 < tn) atomicAdd(&degL[cc[u] >> 17], 1);
            }
        }
        __syncthreads();
    }

    for (int i = tid; i < BSZ * CPG; i += 256) {
        int vl = i >> 4;
        int v = v0 + vl;
        if (v < N) {
            float val = (degL[vl] > 1) ? __uint_as_float(aggL[vl * PAD + (i & 15)]) : 0.f;
            agg[(size_t)v * DH + q * CPG + (i & 15)] = val;
        }
    }
}

// ---------------------------------------------------------------------------
// out = hpart + agg @ W_ffnn[32:64]; wave-uniform weight loads, no LDS.
// ---------------------------------------------------------------------------
__global__ __launch_bounds__(256) void fin(
    const float* __restrict__ hpart, const float* __restrict__ agg,
    const float* __restrict__ W_ffnn, float* __restrict__ out, int N)
{
    const int node = blockIdx.x * 256 + threadIdx.x;
    if (node >= N) return;

    const float4* hr = (const float4*)(hpart + (size_t)node * 32);
    const float4* ar = (const float4*)(agg + (size_t)node * 32);

    float acc[32], a[32];
#pragma unroll
    for (int c4 = 0; c4 < 8; ++c4) {
        float4 v = hr[c4];
        acc[c4 * 4 + 0] = v.x; acc[c4 * 4 + 1] = v.y;
        acc[c4 * 4 + 2] = v.z; acc[c4 * 4 + 3] = v.w;
        float4 w = ar[c4];
        a[c4 * 4 + 0] = w.x; a[c4 * 4 + 1] = w.y;
        a[c4 * 4 + 2] = w.z; a[c4 * 4 + 3] = w.w;
    }

    const float* W2h = W_ffnn + 1024;   // rows 32..63
#pragma unroll
    for (int k = 0; k < 32; ++k) {
        const float hv = a[k];
        const float* wr = W2h + k * 32;
#pragma unroll
        for (int c = 0; c < 32; ++c)
            acc[c] = fmaf(hv, wr[c], acc[c]);
    }

    float4* orow = (float4*)(out + (size_t)node * 32);
#pragma unroll
    for (int c4 = 0; c4 < 8; ++c4)
        orow[c4] = make_float4(acc[c4 * 4 + 0], acc[c4 * 4 + 1],
                               acc[c4 * 4 + 2], acc[c4 * 4 + 3]);
}

// ---------------------------------------------------------------------------
extern "C" void kernel_launch(void* const* d_in, const int* in_sizes, int n_in,
                              void* d_out, int out_size, void* d_ws, size_t ws_size,
                              hipStream_t stream)
{
    const float* feat   = (const float*)d_in[0];
    const int*   src    = (const int*)d_in[1];
    const int*   dst    = (const int*)d_in[2];
    const float* W_in   = (const float*)d_in[3];
    const float* b_in   = (const float*)d_in[4];
    const float* W_nbr  = (const float*)d_in[5];
    const float* b_nbr  = (const float*)d_in[6];
    const float* b_n1   = (const float*)d_in[7];
    const float* W_ffnn = (const float*)d_in[8];
    const float* b_ffnn = (const float*)d_in[9];
    float* out = (float*)d_out;

    const int N = in_sizes[0] / 128;   // 100000 (N <= 131072 required by packing)
    const int E = in_sizes[1];
    const int B = (N + BSZ - 1) / BSZ; // 782 buckets (<= NBP)
    const int ntiles = (N + 15) / 16;  // 6250 16-node tiles

    // u (bf16, channel-split, 6.4MB) aliases d_out (12.8MB): written by the
    // proj path, consumed by bucket_max, then fin overwrites out.
    unsigned short* ub16 = (unsigned short*)out;
    float* hpart   = (float*)d_ws;                    // N*32 f32
    float* agg     = hpart + (size_t)N * DH;          // N*32 f32
    int*   gtotal  = (int*)(agg + (size_t)N * DH);    // NBP
    int*   gbase   = gtotal + NBP;                    // NBP
    int*   gcursor = gbase + NBP;                     // NBP
    unsigned* pairs_g = (unsigned*)(gcursor + NBP);   // 2E u32
    unsigned short* wbf = (unsigned short*)(pairs_g + 2 * (size_t)E);  // 6144 u16

    const int egrid = (E + SCAT_E - 1) / SCAT_E;      // 261
    const int pgrid = (E + PRE_E - 1) / PRE_E;        // 123
    const int jgrid = (ntiles + 4 * TPW - 1) / (4 * TPW);  // 782 proj blocks
    const int npb = (N + 255) / 256;                  // 391

    hipMemsetAsync(gtotal, 0, NBP * sizeof(int), stream);
    pre2<<<pgrid + 1, 256, 0, stream>>>(src, dst, gtotal, E, pgrid,
                                        W_in, W_nbr, W_ffnn, wbf);
    scan_buckets<<<1, 256, 0, stream>>>(gtotal, gbase, gcursor);
    scatproj<<<egrid + jgrid, 256, 0, stream>>>(
        src, dst, gcursor, pairs_g, E, B, egrid,
        feat, wbf, b_in, b_nbr, b_n1, b_ffnn,
        hpart, ub16, N, ntiles);
    bucket_max<<<((B + 3) / 4) * 8, 256, 0, stream>>>(
        pairs_g, gbase, gtotal, (const unsigned*)ub16, agg, N, B);
    fin<<<npb, 256, 0, stream>>>(hpart, agg, W_ffnn, out, N);
}

// Round 18
// 90.538 us; speedup vs baseline: 1.2696x; 1.1680x over previous
//
#include <hip/hip_runtime.h>
#include <hip/hip_bf16.h>

#define DH 32
#define BSZ 128      // nodes per bucket (v_local = 7 bits)
#define NBP 1024     // padded bucket count (N <= 131072 => B <= 1024)
#define SCAT_E 3840  // edges per scatter block
#define SCAT_P (2 * SCAT_E)
#define EPT 15       // edges per thread in scatter (SCAT_E/256)
#define PRE_E 8192   // edges per precount block
#define TS 4096      // pair codes per LDS tile in bmaxfin
#define PAD2 33      // aggL words per node (32 channels + 1 pad)
#define TPW 2        // 16-node tiles per wave in proj

typedef short bf16x8 __attribute__((ext_vector_type(8)));
typedef float f32x4 __attribute__((ext_vector_type(4)));

__device__ __forceinline__ unsigned short f2bf(float x) {
    unsigned b = __float_as_uint(x);
    b += 0x7FFFu + ((b >> 16) & 1u);     // RNE
    return (unsigned short)(b >> 16);
}

// ---------------------------------------------------------------------------
// pre2: blocks [0, pgrid) = per-bucket endpoint histogram; block pgrid =
// weight preconversion to TRANSPOSED bf16 (Wt[c][k]) into wbf.
//   wbf layout: W1t [32][128] @0, W2t [32][32] @4096, Wft [32][32] @5120
// ---------------------------------------------------------------------------
__global__ __launch_bounds__(256) void pre2(
    const int* __restrict__ src, const int* __restrict__ dst,
    int* __restrict__ gtotal, int E, int pgrid,
    const float* __restrict__ W_in, const float* __restrict__ W_nbr,
    const float* __restrict__ W_ffnn, unsigned short* __restrict__ wbf)
{
    __shared__ int hist[NBP];
    const int tid = threadIdx.x;

    if ((int)blockIdx.x == pgrid) {
        for (int i = tid; i < 4096; i += 256) {
            int c = i >> 7, k = i & 127;
            wbf[i] = f2bf(W_in[k * 32 + c]);
        }
        for (int i = tid; i < 1024; i += 256) {
            int c = i >> 5, k = i & 31;
            wbf[4096 + i] = f2bf(W_nbr[k * 32 + c]);
            wbf[5120 + i] = f2bf(W_ffnn[k * 32 + c]);
        }
        return;
    }

    for (int i = tid; i < NBP; i += 256) hist[i] = 0;
    __syncthreads();
    const int e0 = blockIdx.x * PRE_E;
    const int eend = min(e0 + PRE_E, E);
    for (int e = e0 + tid; e < eend; e += 256) {
        atomicAdd(&hist[src[e] >> 7], 1);
        atomicAdd(&hist[dst[e] >> 7], 1);
    }
    __syncthreads();
    for (int i = tid; i < NBP; i += 256)
        if (hist[i] > 0) atomicAdd(&gtotal[i], hist[i]);
}

// ---------------------------------------------------------------------------
// Exclusive scan of gtotal[0..NBP) -> gbase; gcursor = gbase. One block.
// ---------------------------------------------------------------------------
__global__ __launch_bounds__(256) void scan_buckets(
    const int* __restrict__ gtotal, int* __restrict__ gbase,
    int* __restrict__ gcursor)
{
    __shared__ int ss[256];
    const int t = threadIdx.x;
    int v0 = gtotal[4 * t], v1 = gtotal[4 * t + 1];
    int v2 = gtotal[4 * t + 2], v3 = gtotal[4 * t + 3];
    int tsum = v0 + v1 + v2 + v3;
    ss[t] = tsum;
    __syncthreads();
    for (int off = 1; off < 256; off <<= 1) {
        int y = (t >= off) ? ss[t - off] : 0;
        __syncthreads();
        ss[t] += y;
        __syncthreads();
    }
    int e = ss[t] - tsum;
    gbase[4 * t] = e;                    gcursor[4 * t] = e;
    gbase[4 * t + 1] = e + v0;           gcursor[4 * t + 1] = e + v0;
    gbase[4 * t + 2] = e + v0 + v1;      gcursor[4 * t + 2] = e + v0 + v1;
    gbase[4 * t + 3] = e + v0 + v1 + v2; gcursor[4 * t + 3] = e + v0 + v1 + v2;
}

// ---------------------------------------------------------------------------
// FUSED scatproj: blocks [0, egrid) = bucket-granular scatter (38.9 KB LDS);
// blocks [egrid, egrid+jgrid) = MFMA node projection (TPW tiles/wave, wbf
// preconverted weights, 4 KB LDS). u is written NODE-MAJOR bf16 [N][32]
// into workspace (not d_out).
// MFMA fragment layouts (m89-verified): A: row=l&15, k=(l>>4)*8+j;
// B: col=l&15, k=(l>>4)*8+j; C/D: col=l&15, row=(l>>4)*4+reg.
// ---------------------------------------------------------------------------
union SPSmem {
    struct {                                // 38.9 KB (scatter)
        unsigned code[SCAT_P];              // 30 KB
        int cur[NBP];                       // 4 KB (counts -> starts -> ends)
        int gbL[NBP];                       // 4 KB (also scan temp [0..3])
    } sc;
    struct {                                // 4 KB (proj)
        unsigned short htile[4][16 * 32];   // per-wave h bounce
    } pj;
};

__global__ __launch_bounds__(256) void scatproj(
    const int* __restrict__ src, const int* __restrict__ dst,
    int* __restrict__ gcursor, unsigned* __restrict__ pairs_g,
    int E, int B, int egrid,
    const float* __restrict__ feat,
    const unsigned short* __restrict__ wbf,
    const float* __restrict__ b_in, const float* __restrict__ b_nbr,
    const float* __restrict__ b_n1, const float* __restrict__ b_ffnn,
    float* __restrict__ hpart, unsigned short* __restrict__ ub16,
    int N, int ntiles)
{
    __shared__ SPSmem sm;
    const int tid = threadIdx.x;

    if ((int)blockIdx.x < egrid) {
        // ================= scatter path =================
        const int e0 = blockIdx.x * SCAT_E;
        const int eend = min(e0 + SCAT_E, E);
        const int np = 2 * (eend - e0);

        for (int i = tid; i < NBP; i += 256) sm.sc.cur[i] = 0;
        __syncthreads();

        int es[EPT], dr[EPT];
#pragma unroll
        for (int j = 0; j < EPT; ++j) {
            int e = e0 + tid + j * 256;
            bool ok = (e < eend);
            es[j] = ok ? src[e] : -1;
            dr[j] = ok ? dst[e] : -1;
        }
#pragma unroll
        for (int j = 0; j < EPT; ++j) {
            if (es[j] >= 0) {
                atomicAdd(&sm.sc.cur[es[j] >> 7], 1);
                atomicAdd(&sm.sc.cur[dr[j] >> 7], 1);
            }
        }
        __syncthreads();

        // in-place exclusive scan of cur (counts -> starts); shfl-based
        {
            const int lane = tid & 63;
            const int w = tid >> 6;
            int v0 = sm.sc.cur[4 * tid], v1 = sm.sc.cur[4 * tid + 1];
            int v2 = sm.sc.cur[4 * tid + 2], v3 = sm.sc.cur[4 * tid + 3];
            int tsum = v0 + v1 + v2 + v3;
            int x = tsum;
#pragma unroll
            for (int off = 1; off < 64; off <<= 1) {
                int y = __shfl_up(x, off, 64);
                x += (lane >= off) ? y : 0;
            }
            if (lane == 63) sm.sc.gbL[w] = x;   // wave totals (temp use)
            __syncthreads();
            int woff = 0;
#pragma unroll
            for (int k = 0; k < 4; ++k) woff += (k < w) ? sm.sc.gbL[k] : 0;
            int ebase = woff + x - tsum;
            __syncthreads();                    // all reads of cur done
            sm.sc.cur[4 * tid] = ebase;
            sm.sc.cur[4 * tid + 1] = ebase + v0;
            sm.sc.cur[4 * tid + 2] = ebase + v0 + v1;
            sm.sc.cur[4 * tid + 3] = ebase + v0 + v1 + v2;
        }
        __syncthreads();

        // rank + reorder into LDS; bucket low byte in code[31:24]
#pragma unroll
        for (int j = 0; j < EPT; ++j) {
            if (es[j] >= 0) {
                int s = es[j], d = dr[j];
                int bs = s >> 7, bd = d >> 7;
                unsigned cs = ((unsigned)(bs & 255) << 24) |
                              ((unsigned)(s & 127) << 17) | (unsigned)d;
                unsigned cd = ((unsigned)(bd & 255) << 24) |
                              ((unsigned)(d & 127) << 17) | (unsigned)s;
                int p1 = atomicAdd(&sm.sc.cur[bs], 1);
                sm.sc.code[p1] = cs;
                int p2 = atomicAdd(&sm.sc.cur[bd], 1);
                sm.sc.code[p2] = cd;
            }
        }
        __syncthreads();
        // cur[b] = segment END; start(b) = cur[b-1] (segments packed)

        for (int b = tid; b < B; b += 256) {
            int end = sm.sc.cur[b];
            int start = b ? sm.sc.cur[b - 1] : 0;
            int c = end - start;
            if (c > 0) {
                int gw = atomicAdd(&gcursor[b], c);
                sm.sc.gbL[b] = gw - start;
            }
        }
        __syncthreads();

        // coalesced run writes; recover bucket via low byte + containment
        for (int i = tid; i < np; i += 256) {
            unsigned code = sm.sc.code[i];
            int cc = (int)(code >> 24);
#pragma unroll
            for (int k = 0; k < 3; ++k) {
                int hi2 = sm.sc.cur[cc];
                int lo2 = cc ? sm.sc.cur[cc - 1] : 0;
                bool in = (i < hi2) && (i >= lo2);
                cc = in ? cc : cc + 256;
            }
            pairs_g[sm.sc.gbL[cc] + i] = code & 0x00FFFFFFu;
        }
        return;
    }

    // ================= proj path (MFMA, TPW tiles/wave) =================
    const int wid = tid >> 6, lane = tid & 63;
    const int r16 = lane & 15, kg = lane >> 4;
    const int w = ((int)blockIdx.x - egrid) * 4 + wid;
    const int t0 = w * TPW;
    if (t0 >= ntiles) return;                // wave-uniform

    const unsigned short* W1t = wbf;         // [32][128]
    const unsigned short* W2t = wbf + 4096;  // [32][32]
    const unsigned short* Wft = wbf + 5120;  // [32][32]

    // B fragments: single 16B vector loads (preconverted, transposed)
    bf16x8 B1[4][2], B2[2], Bf[2];
#pragma unroll
    for (int ks = 0; ks < 4; ++ks)
#pragma unroll
        for (int ct = 0; ct < 2; ++ct)
            B1[ks][ct] = *(const bf16x8*)&W1t[(ct * 16 + r16) * 128 + ks * 32 + kg * 8];
#pragma unroll
    for (int ct = 0; ct < 2; ++ct) {
        B2[ct] = *(const bf16x8*)&W2t[(ct * 16 + r16) * 32 + kg * 8];
        Bf[ct] = *(const bf16x8*)&Wft[(ct * 16 + r16) * 32 + kg * 8];
    }

    const float b1a = b_in[r16],            b1b = b_in[16 + r16];
    const float b2a = b_nbr[r16] + b_n1[r16];
    const float b2b = b_nbr[16 + r16] + b_n1[16 + r16];
    const float bfa = b_ffnn[r16],          bfb = b_ffnn[16 + r16];

    unsigned short* hl = &sm.pj.htile[wid][0];

#pragma unroll
    for (int i = 0; i < TPW; ++i) {
        const int ti = t0 + i;
        const bool tv = (ti < ntiles);
        const int t = tv ? ti : ntiles - 1;
        const int tbase = t * 16;
        const int nA = tbase + r16;
        const bool okA = tv && (nA < N);
        const float* fr = feat + (size_t)(okA ? nA : 0) * 128;

        // A fragments: 8 consecutive k per lane (two float4 loads + cvt)
        bf16x8 A[4];
#pragma unroll
        for (int ks = 0; ks < 4; ++ks) {
            float4 p0 = make_float4(0.f, 0.f, 0.f, 0.f);
            float4 p1 = make_float4(0.f, 0.f, 0.f, 0.f);
            if (okA) {
                p0 = *(const float4*)(fr + ks * 32 + kg * 8);
                p1 = *(const float4*)(fr + ks * 32 + kg * 8 + 4);
            }
            A[ks][0] = (short)f2bf(p0.x); A[ks][1] = (short)f2bf(p0.y);
            A[ks][2] = (short)f2bf(p0.z); A[ks][3] = (short)f2bf(p0.w);
            A[ks][4] = (short)f2bf(p1.x); A[ks][5] = (short)f2bf(p1.y);
            A[ks][6] = (short)f2bf(p1.z); A[ks][7] = (short)f2bf(p1.w);
        }

        // GEMM1: h-tile = feat-tile @ W_in + b_in
        f32x4 acc0 = {b1a, b1a, b1a, b1a};
        f32x4 acc1 = {b1b, b1b, b1b, b1b};
#pragma unroll
        for (int ks = 0; ks < 4; ++ks) {
            acc0 = __builtin_amdgcn_mfma_f32_16x16x32_bf16(A[ks], B1[ks][0], acc0, 0, 0, 0);
            acc1 = __builtin_amdgcn_mfma_f32_16x16x32_bf16(A[ks], B1[ks][1], acc1, 0, 0, 0);
        }

        // bounce h (bf16) through wave-private LDS: C-layout -> A-layout
#pragma unroll
        for (int r = 0; r < 4; ++r) {
            hl[(kg * 4 + r) * 32 + r16]      = f2bf(acc0[r]);
            hl[(kg * 4 + r) * 32 + 16 + r16] = f2bf(acc1[r]);
        }
        asm volatile("s_waitcnt lgkmcnt(0)" ::: "memory");
        bf16x8 A2 = *reinterpret_cast<const bf16x8*>(&hl[r16 * 32 + kg * 8]);

        // GEMM2 (u) and hpart, K=32 single step each
        f32x4 u0 = {b2a, b2a, b2a, b2a};
        f32x4 u1 = {b2b, b2b, b2b, b2b};
        u0 = __builtin_amdgcn_mfma_f32_16x16x32_bf16(A2, B2[0], u0, 0, 0, 0);
        u1 = __builtin_amdgcn_mfma_f32_16x16x32_bf16(A2, B2[1], u1, 0, 0, 0);
        f32x4 g0 = {bfa, bfa, bfa, bfa};
        f32x4 g1 = {bfb, bfb, bfb, bfb};
        g0 = __builtin_amdgcn_mfma_f32_16x16x32_bf16(A2, Bf[0], g0, 0, 0, 0);
        g1 = __builtin_amdgcn_mfma_f32_16x16x32_bf16(A2, Bf[1], g1, 0, 0, 0);

        // stores: lane covers nodes tbase + kg*4 + r, channel r16 (+16);
        // u is node-major [N][32] bf16 in workspace
#pragma unroll
        for (int r = 0; r < 4; ++r) {
            const int n2 = tbase + kg * 4 + r;
            if (tv && n2 < N) {
                float s0 = 1.0f / (1.0f + __expf(-u0[r]));
                float s1 = 1.0f / (1.0f + __expf(-u1[r]));
                ub16[(size_t)n2 * 32 + r16]       = f2bf(s0);
                ub16[(size_t)n2 * 32 + 16 + r16]  = f2bf(s1);
                hpart[(size_t)n2 * 32 + r16]      = g0[r];
                hpart[(size_t)n2 * 32 + 16 + r16] = g1[r];
            }
        }
    }
}

// ---------------------------------------------------------------------------
// bmaxfin: ONE 512-thread block per bucket. Max-aggregates all 32 channels
// into LDS (16-lane groups, 64B u-row gathers, 16-deep unroll), then computes
// out = hpart + agg @ W_ffnn[32:64] in-block (4 threads/node; aggL reads are
// conflict-free: bank (vl*33+k)%32 = (vl+k)%32).
// ---------------------------------------------------------------------------
__global__ __launch_bounds__(512) void bmaxfin(
    const unsigned* __restrict__ pairs_g, const int* __restrict__ gbase,
    const int* __restrict__ gtotal, const unsigned* __restrict__ ut32,
    const float* __restrict__ hpart, const float* __restrict__ W_ffnn,
    float* __restrict__ out, int N, int B)
{
    __shared__ unsigned aggL[BSZ * PAD2];  // 16.9 KB
    __shared__ int degL[BSZ];              // 0.5 KB
    __shared__ unsigned tile[TS];          // 16 KB
    __shared__ float sWf[1024];            // 4 KB (W_ffnn rows 32..63)

    const int tid = threadIdx.x;
    const int b = blockIdx.x;
    const int v0 = b * BSZ;

    for (int i = tid; i < BSZ * PAD2; i += 512) aggL[i] = 0u;
    for (int i = tid; i < BSZ; i += 512) degL[i] = 0;
    for (int i = tid; i < 1024; i += 512) sWf[i] = W_ffnn[1024 + i];
    __syncthreads();

    const int start = gbase[b];
    const int cnt = gtotal[b];
    const int gg = tid >> 4;       // 32 groups of 16 lanes
    const int cl = tid & 15;

    for (int t0 = 0; t0 < cnt; t0 += TS) {
        const int tn = min(TS, cnt - t0);
        for (int i = tid; i < tn; i += 512) tile[i] = pairs_g[start + t0 + i];
        __syncthreads();

        const int kmax = (tn - gg + 31) >> 5;   // <=0 if gg >= tn
        const int pm = tn - 1;
        for (int kk = 0; kk < kmax; kk += 16) {
            unsigned cc[16], xx[16];
#pragma unroll
            for (int u = 0; u < 16; ++u)
                cc[u] = tile[min(gg + (kk + u) * 32, pm)];
#pragma unroll
            for (int u = 0; u < 16; ++u)
                xx[u] = ut32[(size_t)(cc[u] & 0x1FFFF) * 16 + cl];
#pragma unroll
            for (int u = 0; u < 16; ++u) {
                atomicMax(&aggL[(cc[u] >> 17) * PAD2 + 2 * cl], (xx[u] & 0xFFFFu) << 16);
                atomicMax(&aggL[(cc[u] >> 17) * PAD2 + 2 * cl + 1], xx[u] & 0xFFFF0000u);
            }
            if (cl == 0) {
#pragma unroll
                for (int u = 0; u < 16; ++u)
                    if (gg + (kk + u) * 32 < tn) atomicAdd(&degL[cc[u] >> 17], 1);
            }
        }
        __syncthreads();
    }

    // fused FFN epilogue: 4 threads per node, 8 channels each
    const int vl = tid >> 2;           // 0..127
    const int c0 = (tid & 3) * 8;
    const int v = v0 + vl;
    if (v < N) {
        float acc[8];
        const float4* hr = (const float4*)(hpart + (size_t)v * 32 + c0);
        float4 h0 = hr[0], h1 = hr[1];
        acc[0] = h0.x; acc[1] = h0.y; acc[2] = h0.z; acc[3] = h0.w;
        acc[4] = h1.x; acc[5] = h1.y; acc[6] = h1.z; acc[7] = h1.w;
        if (degL[vl] > 1) {
#pragma unroll
            for (int k = 0; k < 32; ++k) {
                float av = __uint_as_float(aggL[vl * PAD2 + k]);
                const float* wr = &sWf[k * 32 + c0];
#pragma unroll
                for (int j = 0; j < 8; ++j)
                    acc[j] = fmaf(av, wr[j], acc[j]);
            }
        }
        float4* orow = (float4*)(out + (size_t)v * 32 + c0);
        orow[0] = make_float4(acc[0], acc[1], acc[2], acc[3]);
        orow[1] = make_float4(acc[4], acc[5], acc[6], acc[7]);
    }
}

// ---------------------------------------------------------------------------
extern "C" void kernel_launch(void* const* d_in, const int* in_sizes, int n_in,
                              void* d_out, int out_size, void* d_ws, size_t ws_size,
                              hipStream_t stream)
{
    const float* feat   = (const float*)d_in[0];
    const int*   src    = (const int*)d_in[1];
    const int*   dst    = (const int*)d_in[2];
    const float* W_in   = (const float*)d_in[3];
    const float* b_in   = (const float*)d_in[4];
    const float* W_nbr  = (const float*)d_in[5];
    const float* b_nbr  = (const float*)d_in[6];
    const float* b_n1   = (const float*)d_in[7];
    const float* W_ffnn = (const float*)d_in[8];
    const float* b_ffnn = (const float*)d_in[9];
    float* out = (float*)d_out;

    const int N = in_sizes[0] / 128;   // 100000 (N <= 131072 required by packing)
    const int E = in_sizes[1];
    const int B = (N + BSZ - 1) / BSZ; // 782 buckets (<= NBP)
    const int ntiles = (N + 15) / 16;  // 6250 16-node tiles

    // workspace layout (~27.2 MB, all in d_ws; out only written by bmaxfin)
    float* hpart   = (float*)d_ws;                        // N*32 f32  (12.8MB)
    unsigned short* ub16 = (unsigned short*)(hpart + (size_t)N * DH);  // N*32 bf16 (6.4MB)
    int*   gtotal  = (int*)(ub16 + (size_t)N * DH);       // NBP
    int*   gbase   = gtotal + NBP;                        // NBP
    int*   gcursor = gbase + NBP;                         // NBP
    unsigned* pairs_g = (unsigned*)(gcursor + NBP);       // 2E u32 (8MB)
    unsigned short* wbf = (unsigned short*)(pairs_g + 2 * (size_t)E);  // 6144 u16

    const int egrid = (E + SCAT_E - 1) / SCAT_E;          // 261
    const int pgrid = (E + PRE_E - 1) / PRE_E;            // 123
    const int jgrid = (ntiles + 4 * TPW - 1) / (4 * TPW); // 782 proj blocks

    hipMemsetAsync(gtotal, 0, NBP * sizeof(int), stream);
    pre2<<<pgrid + 1, 256, 0, stream>>>(src, dst, gtotal, E, pgrid,
                                        W_in, W_nbr, W_ffnn, wbf);
    scan_buckets<<<1, 256, 0, stream>>>(gtotal, gbase, gcursor);
    scatproj<<<egrid + jgrid, 256, 0, stream>>>(
        src, dst, gcursor, pairs_g, E, B, egrid,
        feat, wbf, b_in, b_nbr, b_n1, b_ffnn,
        hpart, ub16, N, ntiles);
    bmaxfin<<<B, 512, 0, stream>>>(
        pairs_g, gbase, gtotal, (const unsigned*)ub16, hpart, W_ffnn,
        out, N, B);
}

// Round 19
// 90.199 us; speedup vs baseline: 1.2744x; 1.0038x over previous
//
#include <hip/hip_runtime.h>
#include <hip/hip_bf16.h>

#define DH 32
#define BSZ 128      // nodes per bucket (v_local = 7 bits)
#define NBP 1024     // padded bucket count (N <= 131072 => B <= 1024)
#define SCAT_E 3840  // edges per scatter block
#define SCAT_P (2 * SCAT_E)
#define EPT 15       // edges per thread in scatter (SCAT_E/256)
#define PRE_E 8192   // edges per precount block
#define TS 4096      // pair codes per LDS tile in bmaxfin
#define PAD2 33      // aggL words per node (32 channels + 1 pad)
#define TPW 2        // 16-node tiles per wave in proj

typedef short bf16x8 __attribute__((ext_vector_type(8)));
typedef float f32x4 __attribute__((ext_vector_type(4)));

__device__ __forceinline__ unsigned short f2bf(float x) {
    unsigned b = __float_as_uint(x);
    b += 0x7FFFu + ((b >> 16) & 1u);     // RNE
    return (unsigned short)(b >> 16);
}

// ---------------------------------------------------------------------------
// pre2: blocks [0, pgrid) = per-bucket endpoint histogram; block pgrid =
// weight preconversion to TRANSPOSED bf16 (Wt[c][k]) into wbf.
//   wbf layout: W1t [32][128] @0, W2t [32][32] @4096, Wft [32][32] @5120
// ---------------------------------------------------------------------------
__global__ __launch_bounds__(256) void pre2(
    const int* __restrict__ src, const int* __restrict__ dst,
    int* __restrict__ gtotal, int E, int pgrid,
    const float* __restrict__ W_in, const float* __restrict__ W_nbr,
    const float* __restrict__ W_ffnn, unsigned short* __restrict__ wbf)
{
    __shared__ int hist[NBP];
    const int tid = threadIdx.x;

    if ((int)blockIdx.x == pgrid) {
        for (int i = tid; i < 4096; i += 256) {
            int c = i >> 7, k = i & 127;
            wbf[i] = f2bf(W_in[k * 32 + c]);
        }
        for (int i = tid; i < 1024; i += 256) {
            int c = i >> 5, k = i & 31;
            wbf[4096 + i] = f2bf(W_nbr[k * 32 + c]);
            wbf[5120 + i] = f2bf(W_ffnn[k * 32 + c]);
        }
        return;
    }

    for (int i = tid; i < NBP; i += 256) hist[i] = 0;
    __syncthreads();
    const int e0 = blockIdx.x * PRE_E;
    const int eend = min(e0 + PRE_E, E);
    for (int e = e0 + tid; e < eend; e += 256) {
        atomicAdd(&hist[src[e] >> 7], 1);
        atomicAdd(&hist[dst[e] >> 7], 1);
    }
    __syncthreads();
    for (int i = tid; i < NBP; i += 256)
        if (hist[i] > 0) atomicAdd(&gtotal[i], hist[i]);
}

// ---------------------------------------------------------------------------
// Exclusive scan of gtotal[0..NBP) -> gbase; gcursor = gbase. One block.
// ---------------------------------------------------------------------------
__global__ __launch_bounds__(256) void scan_buckets(
    const int* __restrict__ gtotal, int* __restrict__ gbase,
    int* __restrict__ gcursor)
{
    __shared__ int ss[256];
    const int t = threadIdx.x;
    int v0 = gtotal[4 * t], v1 = gtotal[4 * t + 1];
    int v2 = gtotal[4 * t + 2], v3 = gtotal[4 * t + 3];
    int tsum = v0 + v1 + v2 + v3;
    ss[t] = tsum;
    __syncthreads();
    for (int off = 1; off < 256; off <<= 1) {
        int y = (t >= off) ? ss[t - off] : 0;
        __syncthreads();
        ss[t] += y;
        __syncthreads();
    }
    int e = ss[t] - tsum;
    gbase[4 * t] = e;                    gcursor[4 * t] = e;
    gbase[4 * t + 1] = e + v0;           gcursor[4 * t + 1] = e + v0;
    gbase[4 * t + 2] = e + v0 + v1;      gcursor[4 * t + 2] = e + v0 + v1;
    gbase[4 * t + 3] = e + v0 + v1 + v2; gcursor[4 * t + 3] = e + v0 + v1 + v2;
}

// ---------------------------------------------------------------------------
// FUSED scatproj: blocks [0, egrid) = bucket-granular scatter (38.9 KB LDS);
// blocks [egrid, egrid+jgrid) = MFMA node projection (TPW tiles/wave, wbf
// preconverted weights, 4 KB LDS). u is written NODE-MAJOR bf16 [N][32]
// into workspace (not d_out).
// MFMA fragment layouts (m89-verified): A: row=l&15, k=(l>>4)*8+j;
// B: col=l&15, k=(l>>4)*8+j; C/D: col=l&15, row=(l>>4)*4+reg.
// ---------------------------------------------------------------------------
union SPSmem {
    struct {                                // 38.9 KB (scatter)
        unsigned code[SCAT_P];              // 30 KB
        int cur[NBP];                       // 4 KB (counts -> starts -> ends)
        int gbL[NBP];                       // 4 KB (also scan temp [0..3])
    } sc;
    struct {                                // 4 KB (proj)
        unsigned short htile[4][16 * 32];   // per-wave h bounce
    } pj;
};

__global__ __launch_bounds__(256) void scatproj(
    const int* __restrict__ src, const int* __restrict__ dst,
    int* __restrict__ gcursor, unsigned* __restrict__ pairs_g,
    int E, int B, int egrid,
    const float* __restrict__ feat,
    const unsigned short* __restrict__ wbf,
    const float* __restrict__ b_in, const float* __restrict__ b_nbr,
    const float* __restrict__ b_n1, const float* __restrict__ b_ffnn,
    float* __restrict__ hpart, unsigned short* __restrict__ ub16,
    int N, int ntiles)
{
    __shared__ SPSmem sm;
    const int tid = threadIdx.x;

    if ((int)blockIdx.x < egrid) {
        // ================= scatter path =================
        const int e0 = blockIdx.x * SCAT_E;
        const int eend = min(e0 + SCAT_E, E);
        const int np = 2 * (eend - e0);

        for (int i = tid; i < NBP; i += 256) sm.sc.cur[i] = 0;
        __syncthreads();

        int es[EPT], dr[EPT];
#pragma unroll
        for (int j = 0; j < EPT; ++j) {
            int e = e0 + tid + j * 256;
            bool ok = (e < eend);
            es[j] = ok ? src[e] : -1;
            dr[j] = ok ? dst[e] : -1;
        }
#pragma unroll
        for (int j = 0; j < EPT; ++j) {
            if (es[j] >= 0) {
                atomicAdd(&sm.sc.cur[es[j] >> 7], 1);
                atomicAdd(&sm.sc.cur[dr[j] >> 7], 1);
            }
        }
        __syncthreads();

        // in-place exclusive scan of cur (counts -> starts); shfl-based
        {
            const int lane = tid & 63;
            const int w = tid >> 6;
            int v0 = sm.sc.cur[4 * tid], v1 = sm.sc.cur[4 * tid + 1];
            int v2 = sm.sc.cur[4 * tid + 2], v3 = sm.sc.cur[4 * tid + 3];
            int tsum = v0 + v1 + v2 + v3;
            int x = tsum;
#pragma unroll
            for (int off = 1; off < 64; off <<= 1) {
                int y = __shfl_up(x, off, 64);
                x += (lane >= off) ? y : 0;
            }
            if (lane == 63) sm.sc.gbL[w] = x;   // wave totals (temp use)
            __syncthreads();
            int woff = 0;
#pragma unroll
            for (int k = 0; k < 4; ++k) woff += (k < w) ? sm.sc.gbL[k] : 0;
            int ebase = woff + x - tsum;
            __syncthreads();                    // all reads of cur done
            sm.sc.cur[4 * tid] = ebase;
            sm.sc.cur[4 * tid + 1] = ebase + v0;
            sm.sc.cur[4 * tid + 2] = ebase + v0 + v1;
            sm.sc.cur[4 * tid + 3] = ebase + v0 + v1 + v2;
        }
        __syncthreads();

        // rank + reorder into LDS; bucket low byte in code[31:24]
#pragma unroll
        for (int j = 0; j < EPT; ++j) {
            if (es[j] >= 0) {
                int s = es[j], d = dr[j];
                int bs = s >> 7, bd = d >> 7;
                unsigned cs = ((unsigned)(bs & 255) << 24) |
                              ((unsigned)(s & 127) << 17) | (unsigned)d;
                unsigned cd = ((unsigned)(bd & 255) << 24) |
                              ((unsigned)(d & 127) << 17) | (unsigned)s;
                int p1 = atomicAdd(&sm.sc.cur[bs], 1);
                sm.sc.code[p1] = cs;
                int p2 = atomicAdd(&sm.sc.cur[bd], 1);
                sm.sc.code[p2] = cd;
            }
        }
        __syncthreads();
        // cur[b] = segment END; start(b) = cur[b-1] (segments packed)

        for (int b = tid; b < B; b += 256) {
            int end = sm.sc.cur[b];
            int start = b ? sm.sc.cur[b - 1] : 0;
            int c = end - start;
            if (c > 0) {
                int gw = atomicAdd(&gcursor[b], c);
                sm.sc.gbL[b] = gw - start;
            }
        }
        __syncthreads();

        // coalesced run writes; recover bucket via low byte + containment
        for (int i = tid; i < np; i += 256) {
            unsigned code = sm.sc.code[i];
            int cc = (int)(code >> 24);
#pragma unroll
            for (int k = 0; k < 3; ++k) {
                int hi2 = sm.sc.cur[cc];
                int lo2 = cc ? sm.sc.cur[cc - 1] : 0;
                bool in = (i < hi2) && (i >= lo2);
                cc = in ? cc : cc + 256;
            }
            pairs_g[sm.sc.gbL[cc] + i] = code & 0x00FFFFFFu;
        }
        return;
    }

    // ================= proj path (MFMA, TPW tiles/wave) =================
    const int wid = tid >> 6, lane = tid & 63;
    const int r16 = lane & 15, kg = lane >> 4;
    const int w = ((int)blockIdx.x - egrid) * 4 + wid;
    const int t0 = w * TPW;
    if (t0 >= ntiles) return;                // wave-uniform

    const unsigned short* W1t = wbf;         // [32][128]
    const unsigned short* W2t = wbf + 4096;  // [32][32]
    const unsigned short* Wft = wbf + 5120;  // [32][32]

    // B fragments: single 16B vector loads (preconverted, transposed)
    bf16x8 B1[4][2], B2[2], Bf[2];
#pragma unroll
    for (int ks = 0; ks < 4; ++ks)
#pragma unroll
        for (int ct = 0; ct < 2; ++ct)
            B1[ks][ct] = *(const bf16x8*)&W1t[(ct * 16 + r16) * 128 + ks * 32 + kg * 8];
#pragma unroll
    for (int ct = 0; ct < 2; ++ct) {
        B2[ct] = *(const bf16x8*)&W2t[(ct * 16 + r16) * 32 + kg * 8];
        Bf[ct] = *(const bf16x8*)&Wft[(ct * 16 + r16) * 32 + kg * 8];
    }

    const float b1a = b_in[r16],            b1b = b_in[16 + r16];
    const float b2a = b_nbr[r16] + b_n1[r16];
    const float b2b = b_nbr[16 + r16] + b_n1[16 + r16];
    const float bfa = b_ffnn[r16],          bfb = b_ffnn[16 + r16];

    unsigned short* hl = &sm.pj.htile[wid][0];

#pragma unroll
    for (int i = 0; i < TPW; ++i) {
        const int ti = t0 + i;
        const bool tv = (ti < ntiles);
        const int t = tv ? ti : ntiles - 1;
        const int tbase = t * 16;
        const int nA = tbase + r16;
        const bool okA = tv && (nA < N);
        const float* fr = feat + (size_t)(okA ? nA : 0) * 128;

        // A fragments: 8 consecutive k per lane (two float4 loads + cvt)
        bf16x8 A[4];
#pragma unroll
        for (int ks = 0; ks < 4; ++ks) {
            float4 p0 = make_float4(0.f, 0.f, 0.f, 0.f);
            float4 p1 = make_float4(0.f, 0.f, 0.f, 0.f);
            if (okA) {
                p0 = *(const float4*)(fr + ks * 32 + kg * 8);
                p1 = *(const float4*)(fr + ks * 32 + kg * 8 + 4);
            }
            A[ks][0] = (short)f2bf(p0.x); A[ks][1] = (short)f2bf(p0.y);
            A[ks][2] = (short)f2bf(p0.z); A[ks][3] = (short)f2bf(p0.w);
            A[ks][4] = (short)f2bf(p1.x); A[ks][5] = (short)f2bf(p1.y);
            A[ks][6] = (short)f2bf(p1.z); A[ks][7] = (short)f2bf(p1.w);
        }

        // GEMM1: h-tile = feat-tile @ W_in + b_in
        f32x4 acc0 = {b1a, b1a, b1a, b1a};
        f32x4 acc1 = {b1b, b1b, b1b, b1b};
#pragma unroll
        for (int ks = 0; ks < 4; ++ks) {
            acc0 = __builtin_amdgcn_mfma_f32_16x16x32_bf16(A[ks], B1[ks][0], acc0, 0, 0, 0);
            acc1 = __builtin_amdgcn_mfma_f32_16x16x32_bf16(A[ks], B1[ks][1], acc1, 0, 0, 0);
        }

        // bounce h (bf16) through wave-private LDS: C-layout -> A-layout
#pragma unroll
        for (int r = 0; r < 4; ++r) {
            hl[(kg * 4 + r) * 32 + r16]      = f2bf(acc0[r]);
            hl[(kg * 4 + r) * 32 + 16 + r16] = f2bf(acc1[r]);
        }
        asm volatile("s_waitcnt lgkmcnt(0)" ::: "memory");
        bf16x8 A2 = *reinterpret_cast<const bf16x8*>(&hl[r16 * 32 + kg * 8]);

        // GEMM2 (u) and hpart, K=32 single step each
        f32x4 u0 = {b2a, b2a, b2a, b2a};
        f32x4 u1 = {b2b, b2b, b2b, b2b};
        u0 = __builtin_amdgcn_mfma_f32_16x16x32_bf16(A2, B2[0], u0, 0, 0, 0);
        u1 = __builtin_amdgcn_mfma_f32_16x16x32_bf16(A2, B2[1], u1, 0, 0, 0);
        f32x4 g0 = {bfa, bfa, bfa, bfa};
        f32x4 g1 = {bfb, bfb, bfb, bfb};
        g0 = __builtin_amdgcn_mfma_f32_16x16x32_bf16(A2, Bf[0], g0, 0, 0, 0);
        g1 = __builtin_amdgcn_mfma_f32_16x16x32_bf16(A2, Bf[1], g1, 0, 0, 0);

        // stores: lane covers nodes tbase + kg*4 + r, channel r16 (+16);
        // u is node-major [N][32] bf16 in workspace
#pragma unroll
        for (int r = 0; r < 4; ++r) {
            const int n2 = tbase + kg * 4 + r;
            if (tv && n2 < N) {
                float s0 = 1.0f / (1.0f + __expf(-u0[r]));
                float s1 = 1.0f / (1.0f + __expf(-u1[r]));
                ub16[(size_t)n2 * 32 + r16]       = f2bf(s0);
                ub16[(size_t)n2 * 32 + 16 + r16]  = f2bf(s1);
                hpart[(size_t)n2 * 32 + r16]      = g0[r];
                hpart[(size_t)n2 * 32 + 16 + r16] = g1[r];
            }
        }
    }
}

// ---------------------------------------------------------------------------
// bmaxfin: ONE 512-thread block per bucket. Max-aggregates all 32 channels
// into LDS (16-lane groups, 64B u-row gathers, 16-deep unroll), then computes
// out = hpart + agg @ W_ffnn[32:64] in-block (4 threads/node; aggL reads are
// conflict-free: bank (vl*33+k)%32 = (vl+k)%32).
// ---------------------------------------------------------------------------
__global__ __launch_bounds__(512) void bmaxfin(
    const unsigned* __restrict__ pairs_g, const int* __restrict__ gbase,
    const int* __restrict__ gtotal, const unsigned* __restrict__ ut32,
    const float* __restrict__ hpart, const float* __restrict__ W_ffnn,
    float* __restrict__ out, int N, int B)
{
    __shared__ unsigned aggL[BSZ * PAD2];  // 16.9 KB
    __shared__ int degL[BSZ];              // 0.5 KB
    __shared__ unsigned tile[TS];          // 16 KB
    __shared__ float sWf[1024];            // 4 KB (W_ffnn rows 32..63)

    const int tid = threadIdx.x;
    const int b = blockIdx.x;
    const int v0 = b * BSZ;

    for (int i = tid; i < BSZ * PAD2; i += 512) aggL[i] = 0u;
    for (int i = tid; i < BSZ; i += 512) degL[i] = 0;
    for (int i = tid; i < 1024; i += 512) sWf[i] = W_ffnn[1024 + i];
    __syncthreads();

    const int start = gbase[b];
    const int cnt = gtotal[b];
    const int gg = tid >> 4;       // 32 groups of 16 lanes
    const int cl = tid & 15;

    for (int t0 = 0; t0 < cnt; t0 += TS) {
        const int tn = min(TS, cnt - t0);
        for (int i = tid; i < tn; i += 512) tile[i] = pairs_g[start + t0 + i];
        __syncthreads();

        const int kmax = (tn - gg + 31) >> 5;   // <=0 if gg >= tn
        const int pm = tn - 1;
        for (int kk = 0; kk < kmax; kk += 16) {
            unsigned cc[16], xx[16];
#pragma unroll
            for (int u = 0; u < 16; ++u)
                cc[u] = tile[min(gg + (kk + u) * 32, pm)];
#pragma unroll
            for (int u = 0; u < 16; ++u)
                xx[u] = ut32[(size_t)(cc[u] & 0x1FFFF) * 16 + cl];
#pragma unroll
            for (int u = 0; u < 16; ++u) {
                atomicMax(&aggL[(cc[u] >> 17) * PAD2 + 2 * cl], (xx[u] & 0xFFFFu) << 16);
                atomicMax(&aggL[(cc[u] >> 17) * PAD2 + 2 * cl + 1], xx[u] & 0xFFFF0000u);
            }
            if (cl == 0) {
#pragma unroll
                for (int u = 0; u < 16; ++u)
                    if (gg + (kk + u) * 32 < tn) atomicAdd(&degL[cc[u] >> 17], 1);
            }
        }
        __syncthreads();
    }

    // fused FFN epilogue: 4 threads per node, 8 channels each
    const int vl = tid >> 2;           // 0..127
    const int c0 = (tid & 3) * 8;
    const int v = v0 + vl;
    if (v < N) {
        float acc[8];
        const float4* hr = (const float4*)(hpart + (size_t)v * 32 + c0);
        float4 h0 = hr[0], h1 = hr[1];
        acc[0] = h0.x; acc[1] = h0.y; acc[2] = h0.z; acc[3] = h0.w;
        acc[4] = h1.x; acc[5] = h1.y; acc[6] = h1.z; acc[7] = h1.w;
        if (degL[vl] > 1) {
#pragma unroll
            for (int k = 0; k < 32; ++k) {
                float av = __uint_as_float(aggL[vl * PAD2 + k]);
                const float* wr = &sWf[k * 32 + c0];
#pragma unroll
                for (int j = 0; j < 8; ++j)
                    acc[j] = fmaf(av, wr[j], acc[j]);
            }
        }
        float4* orow = (float4*)(out + (size_t)v * 32 + c0);
        orow[0] = make_float4(acc[0], acc[1], acc[2], acc[3]);
        orow[1] = make_float4(acc[4], acc[5], acc[6], acc[7]);
    }
}

// ---------------------------------------------------------------------------
extern "C" void kernel_launch(void* const* d_in, const int* in_sizes, int n_in,
                              void* d_out, int out_size, void* d_ws, size_t ws_size,
                              hipStream_t stream)
{
    const float* feat   = (const float*)d_in[0];
    const int*   src    = (const int*)d_in[1];
    const int*   dst    = (const int*)d_in[2];
    const float* W_in   = (const float*)d_in[3];
    const float* b_in   = (const float*)d_in[4];
    const float* W_nbr  = (const float*)d_in[5];
    const float* b_nbr  = (const float*)d_in[6];
    const float* b_n1   = (const float*)d_in[7];
    const float* W_ffnn = (const float*)d_in[8];
    const float* b_ffnn = (const float*)d_in[9];
    float* out = (float*)d_out;

    const int N = in_sizes[0] / 128;   // 100000 (N <= 131072 required by packing)
    const int E = in_sizes[1];
    const int B = (N + BSZ - 1) / BSZ; // 782 buckets (<= NBP)
    const int ntiles = (N + 15) / 16;  // 6250 16-node tiles

    // workspace layout (~27.2 MB, all in d_ws; out only written by bmaxfin)
    float* hpart   = (float*)d_ws;                        // N*32 f32  (12.8MB)
    unsigned short* ub16 = (unsigned short*)(hpart + (size_t)N * DH);  // N*32 bf16 (6.4MB)
    int*   gtotal  = (int*)(ub16 + (size_t)N * DH);       // NBP
    int*   gbase   = gtotal + NBP;                        // NBP
    int*   gcursor = gbase + NBP;                         // NBP
    unsigned* pairs_g = (unsigned*)(gcursor + NBP);       // 2E u32 (8MB)
    unsigned short* wbf = (unsigned short*)(pairs_g + 2 * (size_t)E);  // 6144 u16

    const int egrid = (E + SCAT_E - 1) / SCAT_E;          // 261
    const int pgrid = (E + PRE_E - 1) / PRE_E;            // 123
    const int jgrid = (ntiles + 4 * TPW - 1) / (4 * TPW); // 782 proj blocks

    hipMemsetAsync(gtotal, 0, NBP * sizeof(int), stream);
    pre2<<<pgrid + 1, 256, 0, stream>>>(src, dst, gtotal, E, pgrid,
                                        W_in, W_nbr, W_ffnn, wbf);
    scan_buckets<<<1, 256, 0, stream>>>(gtotal, gbase, gcursor);
    scatproj<<<egrid + jgrid, 256, 0, stream>>>(
        src, dst, gcursor, pairs_g, E, B, egrid,
        feat, wbf, b_in, b_nbr, b_n1, b_ffnn,
        hpart, ub16, N, ntiles);
    bmaxfin<<<B, 512, 0, stream>>>(
        pairs_g, gbase, gtotal, (const unsigned*)ub16, hpart, W_ffnn,
        out, N, B);
}